// Round 5
// baseline (125.237 us; speedup 1.0000x reference)
//
#include <hip/hip_runtime.h>

// Go board features, fully fused: one block per board (384 threads, ~14KB LDS).
// Labels via double-sweep min-propagation; pooling via wave-per-group with
// 4-way inter-group ILP (4 independent load->reduce->broadcast chains/wave).

constexpr int BOARD = 19;
constexpr int NN = BOARD * BOARD;   // 361
constexpr int DD = 64;
constexpr int NT = 384;             // 6 waves
constexpr int NW = NT / 64;         // 6
constexpr int NQ = NN * (DD / 4);   // 5776 float4 per board

__global__ __launch_bounds__(NT) void go_board(
    const int* __restrict__ stones,   // B*2*361, storage dtype detected at runtime
    const int* __restrict__ ko,       // B*2 int32
    const float* __restrict__ feat,   // B*361*64 f32
    float* __restrict__ o_feats,      // B*361*64
    float* __restrict__ o_libs,       // B*361
    float* __restrict__ o_legal,      // B*361
    float* __restrict__ o_scores)     // B*2
{
    const int b = blockIdx.x;
    const int tid = threadIdx.x;

    __shared__ int s_color[NN];       // 0 black, 1 white, -1 empty
    __shared__ int s_label[NN];
    __shared__ int s_libs[NN];
    __shared__ int s_cnt[NN];         // stones per root label
    __shared__ int s_start[NN];       // exclusive scan of s_cnt
    __shared__ int s_ptr[NN];         // fill cursor
    __shared__ int s_members[NN];     // cell indices grouped by label
    __shared__ int s_glist[NN];       // compacted list of group roots
    __shared__ int s_gs[NN];          // flat: start per compact group id
    __shared__ int s_gc[NN];          // flat: count per compact group id
    __shared__ int s_ng;              // number of groups
    __shared__ int s_sc[2];
    __shared__ int s_changed;
    __shared__ unsigned int s_orw;

    if (tid == 0) { s_orw = 0u; s_sc[0] = 0; s_sc[1] = 0; s_ng = 0; }
    __syncthreads();

    // ---- detect stones storage width (int32 0/1 vs packed bytes vs f32) ----
    {
        unsigned int acc = 0u;
        const unsigned int* w = (const unsigned int*)stones;
        for (int i = tid; i < 768; i += NT) acc |= w[i];
        for (int off = 32; off > 0; off >>= 1)
            acc |= (unsigned int)__shfl_xor((int)acc, off, 64);
        if ((tid & 63) == 0 && acc) atomicOr(&s_orw, acc);
    }
    __syncthreads();
    const unsigned int orw = s_orw;
    const int mode = (orw <= 1u) ? 0 : (((orw & 0xFEFEFEFEu) == 0u) ? 1 : 2);

    // ---- init color / labels / counters ----
    if (tid < NN) {
        int blk, wht;
        const size_t base = (size_t)b * (2 * NN);
        if (mode == 0) {
            blk = stones[base + tid] != 0;
            wht = stones[base + NN + tid] != 0;
        } else if (mode == 1) {
            const unsigned char* s8 = (const unsigned char*)stones;
            blk = s8[base + tid] != 0;
            wht = s8[base + NN + tid] != 0;
        } else {
            const float* sf = (const float*)stones;
            blk = sf[base + tid] != 0.0f;
            wht = sf[base + NN + tid] != 0.0f;
        }
        if (blk) wht = 0;                 // white = stones1 & ~stones0
        s_color[tid] = blk ? 0 : (wht ? 1 : -1);
        s_label[tid] = tid;
        s_libs[tid] = 0;
        s_cnt[tid] = 0;
    }

    // ---- min-label propagation: 2 monotone sweeps per barrier round ----
    // Races are benign (labels only decrease, always within the component).
    auto sweep = [&]() {
        if (tid < NN) {
            const int c = s_color[tid];
            if (c >= 0) {
                int m = s_label[tid];
                const int r = tid / BOARD;
                const int q = tid - r * BOARD;
                if (r > 0         && s_color[tid - BOARD] == c) m = min(m, s_label[tid - BOARD]);
                if (r < BOARD - 1 && s_color[tid + BOARD] == c) m = min(m, s_label[tid + BOARD]);
                if (q > 0         && s_color[tid - 1] == c)     m = min(m, s_label[tid - 1]);
                if (q < BOARD - 1 && s_color[tid + 1] == c)     m = min(m, s_label[tid + 1]);
                m = min(m, s_label[m]);   // pointer-jump step
                if (m < s_label[tid]) { s_label[tid] = m; s_changed = 1; }
            }
        }
    };
    for (int it = 0; it < 64; ++it) {
        __syncthreads();                  // covers init on first pass
        if (tid == 0) s_changed = 0;
        __syncthreads();
        sweep();
        sweep();
        __syncthreads();
        if (!s_changed) break;
    }

    // ---- liberties (dedup in DIRS order), stone counts, group sizes ----
    if (tid < NN) {
        const int c = s_color[tid];
        if (c < 0) {
            const int r = tid / BOARD;
            const int q = tid - r * BOARD;
            const int l0 = (r > 0         && s_color[tid - BOARD] >= 0) ? s_label[tid - BOARD] : NN;
            const int l1 = (r < BOARD - 1 && s_color[tid + BOARD] >= 0) ? s_label[tid + BOARD] : NN;
            const int l2 = (q > 0         && s_color[tid - 1] >= 0)     ? s_label[tid - 1]     : NN;
            const int l3 = (q < BOARD - 1 && s_color[tid + 1] >= 0)     ? s_label[tid + 1]     : NN;
            if (l0 < NN)                                     atomicAdd(&s_libs[l0], 1);
            if (l1 < NN && l1 != l0)                         atomicAdd(&s_libs[l1], 1);
            if (l2 < NN && l2 != l0 && l2 != l1)             atomicAdd(&s_libs[l2], 1);
            if (l3 < NN && l3 != l0 && l3 != l1 && l3 != l2) atomicAdd(&s_libs[l3], 1);
        } else {
            atomicAdd(&s_sc[c], 1);
            atomicAdd(&s_cnt[s_label[tid]], 1);
            if (s_label[tid] == tid) {                 // group root -> compact list
                const int gi = atomicAdd(&s_ng, 1);
                s_glist[gi] = tid;
            }
        }
    }
    __syncthreads();

    // ---- exclusive scan of s_cnt (wave 0 only; 6 chunks of 64) ----
    if (tid < 64) {
        int carry = 0;
        for (int c = 0; c < 6; ++c) {
            const int i = c * 64 + tid;
            const int v = (i < NN) ? s_cnt[i] : 0;
            int x = v;
            for (int off = 1; off < 64; off <<= 1) {
                const int y = __shfl_up(x, off, 64);
                if (tid >= off) x += y;
            }
            if (i < NN) { s_start[i] = carry + x - v; s_ptr[i] = carry + x - v; }
            carry += __shfl(x, 63, 64);
        }
    }
    __syncthreads();

    // ---- fill member lists, flatten group meta, small outputs ----
    const int ng = s_ng;
    if (tid < NN) {
        if (s_color[tid] >= 0) {
            const int pos = atomicAdd(&s_ptr[s_label[tid]], 1);
            s_members[pos] = tid;
        }
        if (tid < ng) {
            const int root = s_glist[tid];
            s_gs[tid] = s_start[root];
            s_gc[tid] = s_cnt[root];
        }
        o_libs[(size_t)b * NN + tid] = (float)s_libs[tid];
        bool legal = (s_color[tid] < 0);
        const int kr = ko[2 * b];
        const int kc = ko[2 * b + 1];
        if (kr >= 0) {
            const int krr = min(max(kr, 0), BOARD - 1);
            const int kcc = min(max(kc, 0), BOARD - 1);
            if (tid == krr * BOARD + kcc) legal = false;
        }
        o_legal[(size_t)b * NN + tid] = legal ? 1.0f : 0.0f;
    }
    if (tid == 0) {
        o_scores[(size_t)b * 2 + 0] = (float)s_sc[0];
        o_scores[(size_t)b * 2 + 1] = (float)s_sc[1];
    }
    __syncthreads();

    const float4* f4 = (const float4*)feat + (size_t)b * NQ;
    float4* o4 = (float4*)o_feats + (size_t)b * NQ;

    // ---- zero-fill empty rows FIRST (fire-and-forget stores drain under
    //      the group chains' load stalls) ----
    for (int p = tid; p < NQ; p += NT) {
        const int cell = p >> 4;
        if (s_color[cell] < 0)
            o4[p] = make_float4(0.f, 0.f, 0.f, 0.f);
    }

    // ---- pooling: wave-per-group, 4 groups in flight per wave ----
    // lane = mi*16 + q: 4 member-lanes x 16 quads; each load/store instruction
    // covers 4 contiguous 256B rows. First member load of all 4 groups is
    // peeled so the 4 global-load chains issue back-to-back.
    const int wave = tid >> 6;
    const int lane = tid & 63;
    const int mi = lane >> 4;
    const int q  = lane & 15;
    for (int g = wave; g < ng; g += 4 * NW) {
        int gs[4], gc[4];
        bool has[4];
        float4 v[4], acc[4];
#pragma unroll
        for (int j = 0; j < 4; ++j) {
            const int gg = g + j * NW;
            const bool ok = gg < ng;
            gs[j] = ok ? s_gs[gg] : 0;
            gc[j] = ok ? s_gc[gg] : 0;
            has[j] = mi < gc[j];
        }
#pragma unroll
        for (int j = 0; j < 4; ++j)       // issue first loads of all chains
            if (has[j]) v[j] = f4[s_members[gs[j] + mi] * 16 + q];
#pragma unroll
        for (int j = 0; j < 4; ++j) {
            acc[j] = make_float4(0.f, 0.f, 0.f, 0.f);
            if (has[j]) {
                acc[j] = v[j];
                for (int k = mi + 4; k < gc[j]; k += 4) {   // rare tail
                    const float4 t = f4[s_members[gs[j] + k] * 16 + q];
                    acc[j].x += t.x; acc[j].y += t.y; acc[j].z += t.z; acc[j].w += t.w;
                }
            }
        }
#pragma unroll
        for (int j = 0; j < 4; ++j) {     // interleaved shfl reduces
            acc[j].x += __shfl_xor(acc[j].x, 16); acc[j].y += __shfl_xor(acc[j].y, 16);
            acc[j].z += __shfl_xor(acc[j].z, 16); acc[j].w += __shfl_xor(acc[j].w, 16);
            acc[j].x += __shfl_xor(acc[j].x, 32); acc[j].y += __shfl_xor(acc[j].y, 32);
            acc[j].z += __shfl_xor(acc[j].z, 32); acc[j].w += __shfl_xor(acc[j].w, 32);
        }
#pragma unroll
        for (int j = 0; j < 4; ++j) {     // broadcast-write group sums
            for (int k = mi; k < gc[j]; k += 4)
                o4[s_members[gs[j] + k] * 16 + q] = acc[j];
        }
    }
}

extern "C" void kernel_launch(void* const* d_in, const int* in_sizes, int n_in,
                              void* d_out, int out_size, void* d_ws, size_t ws_size,
                              hipStream_t stream) {
    // setup_inputs order: stones, ko_points, current_player, features
    const int* stones = (const int*)d_in[0];
    const int* ko     = (const int*)d_in[1];
    const float* feat = (const float*)d_in[3];
    float* out        = (float*)d_out;

    const int B = in_sizes[2];   // current_player has B elements

    float* o_feats  = out;
    float* o_libs   = o_feats + (size_t)B * NN * DD;
    float* o_legal  = o_libs  + (size_t)B * NN;
    float* o_scores = o_legal + (size_t)B * NN;

    go_board<<<B, NT, 0, stream>>>(stones, ko, feat,
                                   o_feats, o_libs, o_legal, o_scores);
}

// Round 7
// 68.372 us; speedup vs baseline: 1.8317x; 1.8317x over previous
//
#include <hip/hip_runtime.h>

// Go board features, fully fused: one block per board (256 threads, ~14KB LDS).
// 8 blocks/CU -> all 2048 boards resident in one generation (label phases
// overlap). Pooling = wave-per-group (round-3 form, compiler-pipelined),
// flattened group meta, non-temporal output stores.

constexpr int BOARD = 19;
constexpr int NN = BOARD * BOARD;   // 361
constexpr int DD = 64;
constexpr int NT = 256;             // 4 waves
constexpr int NW = NT / 64;         // 4
constexpr int NQ = NN * (DD / 4);   // 5776 float4 per board

typedef float f4v __attribute__((ext_vector_type(4)));   // nt-store-compatible

__global__ __launch_bounds__(NT) void go_board(
    const int* __restrict__ stones,   // B*2*361, storage dtype detected at runtime
    const int* __restrict__ ko,       // B*2 int32
    const float* __restrict__ feat,   // B*361*64 f32
    float* __restrict__ o_feats,      // B*361*64
    float* __restrict__ o_libs,       // B*361
    float* __restrict__ o_legal,      // B*361
    float* __restrict__ o_scores)     // B*2
{
    const int b = blockIdx.x;
    const int tid = threadIdx.x;

    __shared__ int s_color[NN];       // 0 black, 1 white, -1 empty
    __shared__ int s_label[NN];
    __shared__ int s_libs[NN];
    __shared__ int s_cnt[NN];         // stones per root label
    __shared__ int s_start[NN];       // exclusive scan of s_cnt
    __shared__ int s_ptr[NN];         // fill cursor
    __shared__ int s_members[NN];     // cell indices grouped by label
    __shared__ int s_glist[NN];       // compacted list of group roots
    __shared__ int s_gs[NN];          // flat: start per compact group id
    __shared__ int s_gc[NN];          // flat: count per compact group id
    __shared__ int s_ng;              // number of groups
    __shared__ int s_sc[2];
    __shared__ int s_changed;
    __shared__ unsigned int s_orw;

    if (tid == 0) { s_orw = 0u; s_sc[0] = 0; s_sc[1] = 0; s_ng = 0; }
    __syncthreads();

    // ---- detect stones storage width (int32 0/1 vs packed bytes vs f32) ----
    {
        unsigned int acc = 0u;
        const unsigned int* w = (const unsigned int*)stones;
        for (int i = tid; i < 768; i += NT) acc |= w[i];
        for (int off = 32; off > 0; off >>= 1)
            acc |= (unsigned int)__shfl_xor((int)acc, off, 64);
        if ((tid & 63) == 0 && acc) atomicOr(&s_orw, acc);
    }
    __syncthreads();
    const unsigned int orw = s_orw;
    const int mode = (orw <= 1u) ? 0 : (((orw & 0xFEFEFEFEu) == 0u) ? 1 : 2);

    // ---- init color / labels / counters ----
    for (int i = tid; i < NN; i += NT) {
        int blk, wht;
        const size_t base = (size_t)b * (2 * NN);
        if (mode == 0) {
            blk = stones[base + i] != 0;
            wht = stones[base + NN + i] != 0;
        } else if (mode == 1) {
            const unsigned char* s8 = (const unsigned char*)stones;
            blk = s8[base + i] != 0;
            wht = s8[base + NN + i] != 0;
        } else {
            const float* sf = (const float*)stones;
            blk = sf[base + i] != 0.0f;
            wht = sf[base + NN + i] != 0.0f;
        }
        if (blk) wht = 0;                 // white = stones1 & ~stones0
        s_color[i] = blk ? 0 : (wht ? 1 : -1);
        s_label[i] = i;
        s_libs[i] = 0;
        s_cnt[i] = 0;
    }

    // ---- min-label propagation (same-color 4-neighbors) + pointer jump ----
    // Races are benign: labels only decrease and stay within the component.
    for (int it = 0; it < 64; ++it) {
        __syncthreads();                  // covers init on first pass
        if (tid == 0) s_changed = 0;
        __syncthreads();
        for (int i = tid; i < NN; i += NT) {
            const int c = s_color[i];
            if (c >= 0) {
                int m = s_label[i];
                const int r = i / BOARD;
                const int q = i - r * BOARD;
                if (r > 0         && s_color[i - BOARD] == c) m = min(m, s_label[i - BOARD]);
                if (r < BOARD - 1 && s_color[i + BOARD] == c) m = min(m, s_label[i + BOARD]);
                if (q > 0         && s_color[i - 1] == c)     m = min(m, s_label[i - 1]);
                if (q < BOARD - 1 && s_color[i + 1] == c)     m = min(m, s_label[i + 1]);
                m = min(m, s_label[m]);   // one pointer-jump step
                if (m < s_label[i]) { s_label[i] = m; s_changed = 1; }
            }
        }
        __syncthreads();
        if (!s_changed) break;
    }

    // ---- liberties (dedup in DIRS order), stone counts, group roots ----
    for (int i = tid; i < NN; i += NT) {
        const int c = s_color[i];
        if (c < 0) {
            const int r = i / BOARD;
            const int q = i - r * BOARD;
            const int l0 = (r > 0         && s_color[i - BOARD] >= 0) ? s_label[i - BOARD] : NN;
            const int l1 = (r < BOARD - 1 && s_color[i + BOARD] >= 0) ? s_label[i + BOARD] : NN;
            const int l2 = (q > 0         && s_color[i - 1] >= 0)     ? s_label[i - 1]     : NN;
            const int l3 = (q < BOARD - 1 && s_color[i + 1] >= 0)     ? s_label[i + 1]     : NN;
            if (l0 < NN)                                     atomicAdd(&s_libs[l0], 1);
            if (l1 < NN && l1 != l0)                         atomicAdd(&s_libs[l1], 1);
            if (l2 < NN && l2 != l0 && l2 != l1)             atomicAdd(&s_libs[l2], 1);
            if (l3 < NN && l3 != l0 && l3 != l1 && l3 != l2) atomicAdd(&s_libs[l3], 1);
        } else {
            atomicAdd(&s_sc[c], 1);
            atomicAdd(&s_cnt[s_label[i]], 1);
            if (s_label[i] == i) {                 // group root -> compact list
                const int gi = atomicAdd(&s_ng, 1);
                s_glist[gi] = i;
            }
        }
    }
    __syncthreads();

    // ---- exclusive scan of s_cnt (wave 0 only; 6 chunks of 64) ----
    if (tid < 64) {
        int carry = 0;
        for (int c = 0; c < 6; ++c) {
            const int i = c * 64 + tid;
            const int v = (i < NN) ? s_cnt[i] : 0;
            int x = v;
            for (int off = 1; off < 64; off <<= 1) {
                const int y = __shfl_up(x, off, 64);
                if (tid >= off) x += y;
            }
            if (i < NN) { s_start[i] = carry + x - v; s_ptr[i] = carry + x - v; }
            carry += __shfl(x, 63, 64);
        }
    }
    __syncthreads();

    // ---- fill member lists, flatten group meta, small outputs ----
    const int ng = s_ng;
    const int kr = ko[2 * b];
    const int kc = ko[2 * b + 1];
    for (int i = tid; i < NN; i += NT) {
        if (s_color[i] >= 0) {
            const int pos = atomicAdd(&s_ptr[s_label[i]], 1);
            s_members[pos] = i;
        }
        if (i < ng) {
            const int root = s_glist[i];
            s_gs[i] = s_start[root];
            s_gc[i] = s_cnt[root];
        }
        o_libs[(size_t)b * NN + i] = (float)s_libs[i];
        bool legal = (s_color[i] < 0);
        if (kr >= 0) {
            const int krr = min(max(kr, 0), BOARD - 1);
            const int kcc = min(max(kc, 0), BOARD - 1);
            if (i == krr * BOARD + kcc) legal = false;
        }
        o_legal[(size_t)b * NN + i] = legal ? 1.0f : 0.0f;
    }
    if (tid == 0) {
        o_scores[(size_t)b * 2 + 0] = (float)s_sc[0];
        o_scores[(size_t)b * 2 + 1] = (float)s_sc[1];
    }
    __syncthreads();

    // ---- pooling: one wave per group; sum once, broadcast to members ----
    // lane = mi*16 + q: 4 member-lanes x 16 quads; each load/store instruction
    // covers 4 contiguous 256B rows. shfl_xor(16,32) reduces over mi.
    const float4* f4 = (const float4*)feat + (size_t)b * NQ;
    f4v* o4 = (f4v*)o_feats + (size_t)b * NQ;
    const int wave = tid >> 6;
    const int lane = tid & 63;
    const int mi = lane >> 4;
    const int q  = lane & 15;
    for (int g = wave; g < ng; g += NW) {
        const int s = s_gs[g];
        const int cnt = s_gc[g];
        float4 acc = make_float4(0.f, 0.f, 0.f, 0.f);
        for (int k = mi; k < cnt; k += 4) {
            const float4 v = f4[s_members[s + k] * 16 + q];
            acc.x += v.x; acc.y += v.y; acc.z += v.z; acc.w += v.w;
        }
        // reduce across the 4 member-lanes (lane strides of 16 within the wave)
        acc.x += __shfl_xor(acc.x, 16); acc.y += __shfl_xor(acc.y, 16);
        acc.z += __shfl_xor(acc.z, 16); acc.w += __shfl_xor(acc.w, 16);
        acc.x += __shfl_xor(acc.x, 32); acc.y += __shfl_xor(acc.y, 32);
        acc.z += __shfl_xor(acc.z, 32); acc.w += __shfl_xor(acc.w, 32);
        // broadcast-write the group sum to every member row (streaming, nt)
        const f4v av = {acc.x, acc.y, acc.z, acc.w};
        for (int k = mi; k < cnt; k += 4) {
            __builtin_nontemporal_store(av, &o4[s_members[s + k] * 16 + q]);
        }
    }
    // zero-fill empty cells (streaming, nt)
    const f4v z = {0.f, 0.f, 0.f, 0.f};
    for (int p = tid; p < NQ; p += NT) {
        const int cell = p >> 4;
        if (s_color[cell] < 0)
            __builtin_nontemporal_store(z, &o4[p]);
    }
}

extern "C" void kernel_launch(void* const* d_in, const int* in_sizes, int n_in,
                              void* d_out, int out_size, void* d_ws, size_t ws_size,
                              hipStream_t stream) {
    // setup_inputs order: stones, ko_points, current_player, features
    const int* stones = (const int*)d_in[0];
    const int* ko     = (const int*)d_in[1];
    const float* feat = (const float*)d_in[3];
    float* out        = (float*)d_out;

    const int B = in_sizes[2];   // current_player has B elements

    float* o_feats  = out;
    float* o_libs   = o_feats + (size_t)B * NN * DD;
    float* o_legal  = o_libs  + (size_t)B * NN;
    float* o_scores = o_legal + (size_t)B * NN;

    go_board<<<B, NT, 0, stream>>>(stones, ko, feat,
                                   o_feats, o_libs, o_legal, o_scores);
}

// Round 8
// 64.603 us; speedup vs baseline: 1.9386x; 1.0583x over previous
//
#include <hip/hip_runtime.h>

// Go board features, fully fused: one block per board (256 threads, ~13KB LDS,
// 8 blocks/CU). Label phase uses packed color|label LDS words (one ds_read per
// neighbor) and double sweeps per barrier round; empty-row output zero-fill is
// issued BEFORE the label loop so its HBM writeback overlaps label compute.
// Pooling = wave-per-group gather + shfl reduce + broadcast nt stores.

constexpr int BOARD = 19;
constexpr int NN = BOARD * BOARD;   // 361
constexpr int DD = 64;
constexpr int NT = 256;             // 4 waves
constexpr int NW = NT / 64;         // 4
constexpr int NQ = NN * (DD / 4);   // 5776 float4 per board

typedef float f4v __attribute__((ext_vector_type(4)));   // nt-store-compatible

// packed cell word: bits[11:10] = color+1 (0 empty, 1 black, 2 white),
// bits[9:0] = label (cell index < 1024). min() on words with equal color
// bits == min on labels; labels only ever decrease within a component.

__global__ __launch_bounds__(NT) void go_board(
    const int* __restrict__ stones,   // B*2*361, storage dtype detected at runtime
    const int* __restrict__ ko,       // B*2 int32
    const float* __restrict__ feat,   // B*361*64 f32
    float* __restrict__ o_feats,      // B*361*64
    float* __restrict__ o_libs,       // B*361
    float* __restrict__ o_legal,      // B*361
    float* __restrict__ o_scores)     // B*2
{
    const int b = blockIdx.x;
    const int tid = threadIdx.x;

    __shared__ int s_cl[NN];          // packed color|label
    __shared__ int s_libs[NN];
    __shared__ int s_cnt[NN];         // stones per root label
    __shared__ int s_start[NN];       // exclusive scan of s_cnt
    __shared__ int s_ptr[NN];         // fill cursor
    __shared__ int s_members[NN];     // cell indices grouped by label
    __shared__ int s_glist[NN];       // compacted list of group roots
    __shared__ int s_gs[NN];          // flat: start per compact group id
    __shared__ int s_gc[NN];          // flat: count per compact group id
    __shared__ int s_ng;              // number of groups
    __shared__ int s_sc[2];
    __shared__ int s_changed;
    __shared__ unsigned int s_orw;

    if (tid == 0) { s_orw = 0u; s_sc[0] = 0; s_sc[1] = 0; s_ng = 0; }
    __syncthreads();

    // ---- detect stones storage width (int32 0/1 vs packed bytes vs f32) ----
    {
        unsigned int acc = 0u;
        const unsigned int* w = (const unsigned int*)stones;
        for (int i = tid; i < 768; i += NT) acc |= w[i];
        for (int off = 32; off > 0; off >>= 1)
            acc |= (unsigned int)__shfl_xor((int)acc, off, 64);
        if ((tid & 63) == 0 && acc) atomicOr(&s_orw, acc);
    }
    __syncthreads();
    const unsigned int orw = s_orw;
    const int mode = (orw <= 1u) ? 0 : (((orw & 0xFEFEFEFEu) == 0u) ? 1 : 2);

    // ---- init packed color|label + counters ----
    for (int i = tid; i < NN; i += NT) {
        int blk, wht;
        const size_t base = (size_t)b * (2 * NN);
        if (mode == 0) {
            blk = stones[base + i] != 0;
            wht = stones[base + NN + i] != 0;
        } else if (mode == 1) {
            const unsigned char* s8 = (const unsigned char*)stones;
            blk = s8[base + i] != 0;
            wht = s8[base + NN + i] != 0;
        } else {
            const float* sf = (const float*)stones;
            blk = sf[base + i] != 0.0f;
            wht = sf[base + NN + i] != 0.0f;
        }
        const int cc = blk ? 1 : ((wht && !blk) ? 2 : 0);  // white = s1 & ~s0
        s_cl[i] = (cc << 10) | i;
        s_libs[i] = 0;
        s_cnt[i] = 0;
    }
    __syncthreads();

    // ---- zero-fill empty output rows NOW: nt stores ack at L2 and write
    //      back to HBM while the label loop below runs (color bits are
    //      final; label updates don't touch them -> race-free) ----
    f4v* o4 = (f4v*)o_feats + (size_t)b * NQ;
    {
        const f4v z = {0.f, 0.f, 0.f, 0.f};
        for (int p = tid; p < NQ; p += NT) {
            const int cell = p >> 4;
            if ((s_cl[cell] >> 10) == 0)
                __builtin_nontemporal_store(z, &o4[p]);
        }
    }

    // ---- min-label propagation: packed words, 2 sweeps per barrier round ----
    auto sweep = [&]() {
        for (int i = tid; i < NN; i += NT) {
            const int w = s_cl[i];
            if (w >> 10) {
                int m = w;
                const int r = i / BOARD;
                const int q = i - r * BOARD;
                if (r > 0)         { const int nw = s_cl[i - BOARD]; if (!((nw ^ w) >> 10)) m = min(m, nw); }
                if (r < BOARD - 1) { const int nw = s_cl[i + BOARD]; if (!((nw ^ w) >> 10)) m = min(m, nw); }
                if (q > 0)         { const int nw = s_cl[i - 1];     if (!((nw ^ w) >> 10)) m = min(m, nw); }
                if (q < BOARD - 1) { const int nw = s_cl[i + 1];     if (!((nw ^ w) >> 10)) m = min(m, nw); }
                m = min(m, s_cl[m & 1023]);   // pointer jump (same component)
                if (m < w) { s_cl[i] = m; s_changed = 1; }
            }
        }
    };
    for (int it = 0; it < 64; ++it) {
        __syncthreads();
        if (tid == 0) s_changed = 0;
        __syncthreads();
        sweep();
        sweep();                          // monotone -> no barrier needed between
        __syncthreads();
        if (!s_changed) break;
    }

    // ---- liberties (dedup in DIRS order), stone counts, group roots ----
    for (int i = tid; i < NN; i += NT) {
        const int w = s_cl[i];
        if ((w >> 10) == 0) {             // empty: scatter liberties
            const int r = i / BOARD;
            const int q = i - r * BOARD;
            int l0 = NN, l1 = NN, l2 = NN, l3 = NN;
            if (r > 0)         { const int nw = s_cl[i - BOARD]; if (nw >> 10) l0 = nw & 1023; }
            if (r < BOARD - 1) { const int nw = s_cl[i + BOARD]; if (nw >> 10) l1 = nw & 1023; }
            if (q > 0)         { const int nw = s_cl[i - 1];     if (nw >> 10) l2 = nw & 1023; }
            if (q < BOARD - 1) { const int nw = s_cl[i + 1];     if (nw >> 10) l3 = nw & 1023; }
            if (l0 < NN)                                     atomicAdd(&s_libs[l0], 1);
            if (l1 < NN && l1 != l0)                         atomicAdd(&s_libs[l1], 1);
            if (l2 < NN && l2 != l0 && l2 != l1)             atomicAdd(&s_libs[l2], 1);
            if (l3 < NN && l3 != l0 && l3 != l1 && l3 != l2) atomicAdd(&s_libs[l3], 1);
        } else {
            atomicAdd(&s_sc[(w >> 10) - 1], 1);
            const int lab = w & 1023;
            atomicAdd(&s_cnt[lab], 1);
            if (lab == i) {               // group root -> compact list
                const int gi = atomicAdd(&s_ng, 1);
                s_glist[gi] = i;
            }
        }
    }
    __syncthreads();

    // ---- exclusive scan of s_cnt (wave 0 only; 6 chunks of 64) ----
    if (tid < 64) {
        int carry = 0;
        for (int c = 0; c < 6; ++c) {
            const int i = c * 64 + tid;
            const int v = (i < NN) ? s_cnt[i] : 0;
            int x = v;
            for (int off = 1; off < 64; off <<= 1) {
                const int y = __shfl_up(x, off, 64);
                if (tid >= off) x += y;
            }
            if (i < NN) { s_start[i] = carry + x - v; s_ptr[i] = carry + x - v; }
            carry += __shfl(x, 63, 64);
        }
    }
    __syncthreads();

    // ---- fill member lists, flatten group meta, small outputs ----
    const int ng = s_ng;
    const int kr = ko[2 * b];
    const int kc = ko[2 * b + 1];
    for (int i = tid; i < NN; i += NT) {
        const int w = s_cl[i];
        if (w >> 10) {
            const int pos = atomicAdd(&s_ptr[w & 1023], 1);
            s_members[pos] = i;
        }
        if (i < ng) {
            const int root = s_glist[i];
            s_gs[i] = s_start[root];
            s_gc[i] = s_cnt[root];
        }
        o_libs[(size_t)b * NN + i] = (float)s_libs[i];
        bool legal = ((w >> 10) == 0);
        if (kr >= 0) {
            const int krr = min(max(kr, 0), BOARD - 1);
            const int kcc = min(max(kc, 0), BOARD - 1);
            if (i == krr * BOARD + kcc) legal = false;
        }
        o_legal[(size_t)b * NN + i] = legal ? 1.0f : 0.0f;
    }
    if (tid == 0) {
        o_scores[(size_t)b * 2 + 0] = (float)s_sc[0];
        o_scores[(size_t)b * 2 + 1] = (float)s_sc[1];
    }
    __syncthreads();

    // ---- pooling: one wave per group; sum once, broadcast to members ----
    // lane = mi*16 + q: 4 member-lanes x 16 quads; each load/store instruction
    // covers 4 contiguous 256B rows. shfl_xor(16,32) reduces over mi.
    const float4* f4 = (const float4*)feat + (size_t)b * NQ;
    const int wave = tid >> 6;
    const int lane = tid & 63;
    const int mi = lane >> 4;
    const int q  = lane & 15;
    for (int g = wave; g < ng; g += NW) {
        const int s = s_gs[g];
        const int cnt = s_gc[g];
        float4 acc = make_float4(0.f, 0.f, 0.f, 0.f);
        for (int k = mi; k < cnt; k += 4) {
            const float4 v = f4[s_members[s + k] * 16 + q];
            acc.x += v.x; acc.y += v.y; acc.z += v.z; acc.w += v.w;
        }
        // reduce across the 4 member-lanes (lane strides of 16 within the wave)
        acc.x += __shfl_xor(acc.x, 16); acc.y += __shfl_xor(acc.y, 16);
        acc.z += __shfl_xor(acc.z, 16); acc.w += __shfl_xor(acc.w, 16);
        acc.x += __shfl_xor(acc.x, 32); acc.y += __shfl_xor(acc.y, 32);
        acc.z += __shfl_xor(acc.z, 32); acc.w += __shfl_xor(acc.w, 32);
        // broadcast-write the group sum to every member row (streaming, nt)
        const f4v av = {acc.x, acc.y, acc.z, acc.w};
        for (int k = mi; k < cnt; k += 4) {
            __builtin_nontemporal_store(av, &o4[s_members[s + k] * 16 + q]);
        }
    }
}

extern "C" void kernel_launch(void* const* d_in, const int* in_sizes, int n_in,
                              void* d_out, int out_size, void* d_ws, size_t ws_size,
                              hipStream_t stream) {
    // setup_inputs order: stones, ko_points, current_player, features
    const int* stones = (const int*)d_in[0];
    const int* ko     = (const int*)d_in[1];
    const float* feat = (const float*)d_in[3];
    float* out        = (float*)d_out;

    const int B = in_sizes[2];   // current_player has B elements

    float* o_feats  = out;
    float* o_libs   = o_feats + (size_t)B * NN * DD;
    float* o_legal  = o_libs  + (size_t)B * NN;
    float* o_scores = o_legal + (size_t)B * NN;

    go_board<<<B, NT, 0, stream>>>(stones, ko, feat,
                                   o_feats, o_libs, o_legal, o_scores);
}